// Round 6
// baseline (334.485 us; speedup 1.0000x reference)
//
#include <hip/hip_runtime.h>
#include <hip/hip_bf16.h>
#include <stdint.h>

// DIAGNOSTIC ROUND: GEMM v4 unchanged; two combine variants, each repeated
// 3x in-kernel (idempotent; asm barrier defeats DSE) so both appear in the
// rocprof top-5 with real dur/FETCH/WRITE counters.
//   A (scat): R4-best geometry — nt stores, q[12] hoisted, 4KB granules.
//   B (mono): fill-like — 1024 blocks, 288KB monotone contiguous per block.

typedef __attribute__((ext_vector_type(8))) short short8;
typedef __attribute__((ext_vector_type(4))) short short4v;
typedef __attribute__((ext_vector_type(4))) float f32x4;

#define L_DIM 96
#define B_DIM 16
#define C_DIM 512
#define M_DIM 1536
#define K_DIM 512
#define N_DIM 1024

#define TM 96
#define TN 64
#define KPH 256
#define ASTR 264

__device__ inline unsigned short f32_to_bf16(float f) {
    union { float f; uint32_t u; } c; c.f = f;
    uint32_t u = c.u;
    uint32_t r = (u + 0x7FFFu + ((u >> 16) & 1u)) >> 16;  // RNE
    return (unsigned short)r;
}

// ---- fused GEMM (identical to R4) ----
__global__ __launch_bounds__(256) void gemm_pq(const float* __restrict__ x,
                                               const float* __restrict__ W,
                                               const float* __restrict__ bias,
                                               float* __restrict__ C) {
    __shared__ unsigned short As[TM * ASTR];
    __shared__ unsigned short Bs[TN * ASTR];
    const int bm = blockIdx.x;
    const int bn = blockIdx.y;
    const int tid = threadIdx.x;
    const int lane = tid & 63;
    const int w  = tid >> 6;
    const int wr = w >> 1, wc = w & 1;
    const int l15 = lane & 15, l4 = lane >> 4;

    const float* xbase = x + (size_t)(bm * TM) * K_DIM;
    const float* wbase = (bn < 8) ? (W + (size_t)(bn * TN) * N_DIM)
                                  : (W + (size_t)(bn * TN - C_DIM) * N_DIM + C_DIM);

    f32x4 acc[3][2] = {};

    for (int ph = 0; ph < 2; ++ph) {
        __syncthreads();
#pragma unroll 4
        for (int r = 0; r < 24; ++r) {
            int q = tid + 256 * r;
            int row = q >> 6, kc4 = (q & 63) << 2;
            f32x4 v = *(const f32x4*)(xbase + (size_t)row * K_DIM + ph * KPH + kc4);
            short4v s;
#pragma unroll
            for (int e = 0; e < 4; ++e) {
                float f = v[e];
                f = f > 0.f ? f : 0.1f * f;
                s[e] = (short)f32_to_bf16(f);
            }
            *(short4v*)(&As[row * ASTR + kc4]) = s;
        }
#pragma unroll 4
        for (int r = 0; r < 16; ++r) {
            int q = tid + 256 * r;
            int row = q >> 6, kc4 = (q & 63) << 2;
            f32x4 v = *(const f32x4*)(wbase + (size_t)row * N_DIM + ph * KPH + kc4);
            short4v s;
#pragma unroll
            for (int e = 0; e < 4; ++e) s[e] = (short)f32_to_bf16(v[e]);
            *(short4v*)(&Bs[row * ASTR + kc4]) = s;
        }
        __syncthreads();
#pragma unroll
        for (int kt = 0; kt < 8; ++kt) {
            short8 a[3], b[2];
#pragma unroll
            for (int m = 0; m < 3; ++m)
                a[m] = *(const short8*)(&As[(wr * 48 + m * 16 + l15) * ASTR + kt * 32 + l4 * 8]);
#pragma unroll
            for (int n = 0; n < 2; ++n)
                b[n] = *(const short8*)(&Bs[(wc * 32 + n * 16 + l15) * ASTR + kt * 32 + l4 * 8]);
#pragma unroll
            for (int m = 0; m < 3; ++m)
#pragma unroll
                for (int n = 0; n < 2; ++n)
                    acc[m][n] = __builtin_amdgcn_mfma_f32_16x16x32_bf16(a[m], b[n], acc[m][n], 0, 0, 0);
        }
    }

#pragma unroll
    for (int m = 0; m < 3; ++m) {
#pragma unroll
        for (int n = 0; n < 2; ++n) {
            int col = bn * TN + wc * 32 + n * 16 + l15;
            float bv = (bn < 8) ? bias[col] : 0.f;
#pragma unroll
            for (int e = 0; e < 4; ++e) {
                int row = bm * TM + wr * 48 + m * 16 + l4 * 4 + e;
                C[(size_t)row * N_DIM + col] = acc[m][n][e] + bv;
            }
        }
    }
}

// ---- variant A: R4 combine geometry, 3 reps ----
__global__ __launch_bounds__(256) void combine_scat(const f32x4* __restrict__ PQ4,
                                                    f32x4* __restrict__ out4) {
    const int jh   = blockIdx.x & 7;
    const int rest = blockIdx.x >> 3;
    const int g    = rest * 256 + threadIdx.x;
    const uint32_t c4 = (uint32_t)g & 127u;
    const uint32_t rg = (uint32_t)g >> 7;
    const uint32_t b  = rg & 15u;
    const uint32_t i  = rg >> 4;

    const f32x4 p = PQ4[(size_t)rg * 256u + c4];
    const int j0 = jh * 12;
    const f32x4* qb = PQ4 + ((size_t)(j0 * 16u + b)) * 256u + 128u + c4;

    f32x4 q[12];
#pragma unroll
    for (int j = 0; j < 12; ++j) q[j] = qb[(size_t)j * 4096u];

    f32x4* ob = out4 + ((size_t)(i * 96u + (uint32_t)j0) * 16u + b) * 128u + c4;
#pragma clang loop unroll(disable)
    for (int rep = 0; rep < 3; ++rep) {
        f32x4* o = ob;
        asm volatile("" : "+v"(o));           // opaque ptr: defeat cross-rep DSE
#pragma unroll
        for (int j = 0; j < 12; ++j)
            __builtin_nontemporal_store(p + q[j], o + (size_t)j * 2048u);
    }
}

// ---- variant B: fill-like monotone — block owns 9 contiguous (i,j) pairs
//      (288 KB monotone); thread covers 8 (b,c4) slots; 3 reps ----
__global__ __launch_bounds__(256) void combine_mono(const f32x4* __restrict__ PQ4,
                                                    f32x4* __restrict__ out4) {
    const int pair0 = blockIdx.x * 9;          // 1024 blocks x 9 = 9216 pairs
    const uint32_t t = threadIdx.x;

    uint32_t poff[8], qoff[8];
#pragma unroll
    for (int s = 0; s < 8; ++s) {
        uint32_t v  = t + 256u * s;            // 0..2047
        uint32_t b  = v >> 7;
        uint32_t c4 = v & 127u;
        poff[s] = b * 256u + c4;               // + i*4096 -> P
        qoff[s] = b * 256u + 128u + c4;        // + j*4096 -> Q
    }

#pragma clang loop unroll(disable)
    for (int rep = 0; rep < 3; ++rep) {
        f32x4* o = out4;
        asm volatile("" : "+v"(o));
        int cur_i = -1;
        f32x4 p[8];
#pragma clang loop unroll(disable)
        for (int pp = 0; pp < 9; ++pp) {
            int pair = pair0 + pp;
            int i = (unsigned)pair / 96u;
            int j = (unsigned)pair - (unsigned)i * 96u;
            if (i != cur_i) {
                cur_i = i;
#pragma unroll
                for (int s = 0; s < 8; ++s) p[s] = PQ4[(size_t)i * 4096u + poff[s]];
            }
            f32x4 q[8];
#pragma unroll
            for (int s = 0; s < 8; ++s) q[s] = PQ4[(size_t)j * 4096u + qoff[s]];
            f32x4* ob = o + (size_t)pair * 2048u + t;
#pragma unroll
            for (int s = 0; s < 8; ++s)
                __builtin_nontemporal_store(p[s] + q[s], ob + 256u * s);
        }
    }
}

extern "C" void kernel_launch(void* const* d_in, const int* in_sizes, int n_in,
                              void* d_out, int out_size, void* d_ws, size_t ws_size,
                              hipStream_t stream) {
    const float* x    = (const float*)d_in[0];
    const float* W    = (const float*)d_in[1];
    const float* bias = (const float*)d_in[2];
    float* out = (float*)d_out;

    float* PQ = (float*)d_ws;                  // 1536 x 1024 f32

    dim3 g(M_DIM / TM, N_DIM / TN);            // 256 blocks
    gemm_pq<<<g, 256, 0, stream>>>(x, W, bias, PQ);
    combine_scat<<<6144, 256, 0, stream>>>((const f32x4*)PQ, (f32x4*)out);
    combine_mono<<<1024, 256, 0, stream>>>((const f32x4*)PQ, (f32x4*)out);
}

// Round 7
// 71.376 us; speedup vs baseline: 4.6862x; 4.6862x over previous
//
#include <hip/hip_runtime.h>
#include <hip/hip_bf16.h>
#include <stdint.h>

// CatLayer: out[i,j,b,c] = sum_k W[c,k] * leaky(concat(x_i, x_j))[k] + bias[c]
// Factorization: out[i,j,b,c] = P[i*16+b, c] + Q[j*16+b, c]  (bias folded into P)
//   [P|Q] = leaky(x).reshape(1536,512) @ [W[:, :512]^T | W[:, 512:]^T]
// K1: fused convert+GEMM, 96x64 tiles, 256 blocks (1/CU), K in 2 phases.
// K2: combine — EXACT R4 geometry (6144 blocks, q[12] hoisted, 4KB granules
//     at 32KB stride) with ONE change: plain stores instead of nt.
//     Evidence: fill kernel hits 7.0 TB/s with plain stores + same pattern;
//     all nt variants cap at 4.9-5.5 TB/s; R6 counters show reads are
//     cache-served (FETCH 15 MB/rep) so only the store path differs.

typedef __attribute__((ext_vector_type(8))) short short8;
typedef __attribute__((ext_vector_type(4))) short short4v;
typedef __attribute__((ext_vector_type(4))) float f32x4;

#define L_DIM 96
#define B_DIM 16
#define C_DIM 512
#define M_DIM 1536   // L*B
#define K_DIM 512
#define N_DIM 1024   // 2*C

#define TM 96
#define TN 64
#define KPH 256      // K per LDS phase
#define ASTR 264     // LDS row stride in bf16 elems (256 + 8 pad)

__device__ inline unsigned short f32_to_bf16(float f) {
    union { float f; uint32_t u; } c; c.f = f;
    uint32_t u = c.u;
    uint32_t r = (u + 0x7FFFu + ((u >> 16) & 1u)) >> 16;  // RNE
    return (unsigned short)r;
}

// ---- fused GEMM (identical to R4) ----
__global__ __launch_bounds__(256) void gemm_pq(const float* __restrict__ x,
                                               const float* __restrict__ W,
                                               const float* __restrict__ bias,
                                               float* __restrict__ C) {
    __shared__ unsigned short As[TM * ASTR];   // 50688 B
    __shared__ unsigned short Bs[TN * ASTR];   // 33792 B
    const int bm = blockIdx.x;            // 0..15
    const int bn = blockIdx.y;            // 0..15
    const int tid = threadIdx.x;
    const int lane = tid & 63;
    const int w  = tid >> 6;
    const int wr = w >> 1, wc = w & 1;    // wave -> 48x32 quadrant
    const int l15 = lane & 15, l4 = lane >> 4;

    const float* xbase = x + (size_t)(bm * TM) * K_DIM;
    const float* wbase = (bn < 8) ? (W + (size_t)(bn * TN) * N_DIM)
                                  : (W + (size_t)(bn * TN - C_DIM) * N_DIM + C_DIM);

    f32x4 acc[3][2] = {};

    for (int ph = 0; ph < 2; ++ph) {
        __syncthreads();
#pragma unroll 4
        for (int r = 0; r < 24; ++r) {
            int q = tid + 256 * r;
            int row = q >> 6, kc4 = (q & 63) << 2;
            f32x4 v = *(const f32x4*)(xbase + (size_t)row * K_DIM + ph * KPH + kc4);
            short4v s;
#pragma unroll
            for (int e = 0; e < 4; ++e) {
                float f = v[e];
                f = f > 0.f ? f : 0.1f * f;
                s[e] = (short)f32_to_bf16(f);
            }
            *(short4v*)(&As[row * ASTR + kc4]) = s;
        }
#pragma unroll 4
        for (int r = 0; r < 16; ++r) {
            int q = tid + 256 * r;
            int row = q >> 6, kc4 = (q & 63) << 2;
            f32x4 v = *(const f32x4*)(wbase + (size_t)row * N_DIM + ph * KPH + kc4);
            short4v s;
#pragma unroll
            for (int e = 0; e < 4; ++e) s[e] = (short)f32_to_bf16(v[e]);
            *(short4v*)(&Bs[row * ASTR + kc4]) = s;
        }
        __syncthreads();
#pragma unroll
        for (int kt = 0; kt < 8; ++kt) {
            short8 a[3], b[2];
#pragma unroll
            for (int m = 0; m < 3; ++m)
                a[m] = *(const short8*)(&As[(wr * 48 + m * 16 + l15) * ASTR + kt * 32 + l4 * 8]);
#pragma unroll
            for (int n = 0; n < 2; ++n)
                b[n] = *(const short8*)(&Bs[(wc * 32 + n * 16 + l15) * ASTR + kt * 32 + l4 * 8]);
#pragma unroll
            for (int m = 0; m < 3; ++m)
#pragma unroll
                for (int n = 0; n < 2; ++n)
                    acc[m][n] = __builtin_amdgcn_mfma_f32_16x16x32_bf16(a[m], b[n], acc[m][n], 0, 0, 0);
        }
    }

#pragma unroll
    for (int m = 0; m < 3; ++m) {
#pragma unroll
        for (int n = 0; n < 2; ++n) {
            int col = bn * TN + wc * 32 + n * 16 + l15;
            float bv = (bn < 8) ? bias[col] : 0.f;
#pragma unroll
            for (int e = 0; e < 4; ++e) {
                int row = bm * TM + wr * 48 + m * 16 + l4 * 4 + e;
                C[(size_t)row * N_DIM + col] = acc[m][n][e] + bv;
            }
        }
    }
}

// ---- combine: R4 geometry exactly; plain stores (single variable vs R4) ----
__global__ __launch_bounds__(256) void combine_k(const f32x4* __restrict__ PQ4,
                                                 f32x4* __restrict__ out4) {
    const int jh   = blockIdx.x & 7;              // j-octant
    const int rest = blockIdx.x >> 3;             // 0..767
    const int g    = rest * 256 + threadIdx.x;    // 0..196607
    const uint32_t c4 = (uint32_t)g & 127u;
    const uint32_t rg = (uint32_t)g >> 7;         // i*16+b, 0..1535
    const uint32_t b  = rg & 15u;
    const uint32_t i  = rg >> 4;

    const f32x4 p = PQ4[(size_t)rg * 256u + c4];          // P[i*16+b][c4]
    const int j0 = jh * 12;
    const f32x4* qb = PQ4 + ((size_t)(j0 * 16u + b)) * 256u + 128u + c4;

    f32x4 q[12];
#pragma unroll
    for (int j = 0; j < 12; ++j) q[j] = qb[(size_t)j * 4096u];   // +16 rows per j

    f32x4* ob = out4 + ((size_t)(i * 96u + (uint32_t)j0) * 16u + b) * 128u + c4;
#pragma unroll
    for (int j = 0; j < 12; ++j)
        ob[(size_t)j * 2048u] = p + q[j];         // plain store (was nt in R4)
}

extern "C" void kernel_launch(void* const* d_in, const int* in_sizes, int n_in,
                              void* d_out, int out_size, void* d_ws, size_t ws_size,
                              hipStream_t stream) {
    const float* x    = (const float*)d_in[0];
    const float* W    = (const float*)d_in[1];
    const float* bias = (const float*)d_in[2];
    float* out = (float*)d_out;

    float* PQ = (float*)d_ws;                      // 1536 x 1024 f32 = 6,291,456 B

    dim3 g(M_DIM / TM, N_DIM / TN);                // 16 x 16 = 256 blocks
    gemm_pq<<<g, 256, 0, stream>>>(x, W, bias, PQ);
    combine_k<<<6144, 256, 0, stream>>>((const f32x4*)PQ, (f32x4*)out);
}

// Round 8
// 65.179 us; speedup vs baseline: 5.1318x; 1.0951x over previous
//
#include <hip/hip_runtime.h>
#include <hip/hip_bf16.h>
#include <stdint.h>

// CatLayer: out[i,j,b,c] = sum_k W[c,k] * leaky(concat(x_i, x_j))[k] + bias[c]
// Factorization: out[i,j,b,c] = P[i*16+b, c] + Q[j*16+b, c]  (bias folded into P)
//   [P|Q] = leaky(x).reshape(1536,512) @ [W[:, :512]^T | W[:, 512:]^T]
// K1: fused convert+GEMM, 64x64 tiles, 384 blocks (2/CU, 8 waves/CU), K in
//     2 phases of 256 (was 96x64, 1/CU, 4 waves/CU — latency-exposed).
// K2: combine — R4-best byte-for-byte: nt stores, q[12] hoisted, 6144 blocks,
//     4KB granules at 32KB stride. Measured 5.0 TB/s writes + ~5 TB/s L2
//     reads = mixed-stream fabric ceiling (nt>plain: R7 A/B; geometry flat:
//     R6; reads cache-served: FETCH 15MB/rep).

typedef __attribute__((ext_vector_type(8))) short short8;
typedef __attribute__((ext_vector_type(4))) short short4v;
typedef __attribute__((ext_vector_type(4))) float f32x4;

#define L_DIM 96
#define B_DIM 16
#define C_DIM 512
#define M_DIM 1536   // L*B
#define K_DIM 512
#define N_DIM 1024   // 2*C

#define TM 64
#define TN 64
#define KPH 256      // K per LDS phase
#define ASTR 264     // LDS row stride in bf16 elems (256 + 8 pad)

__device__ inline unsigned short f32_to_bf16(float f) {
    union { float f; uint32_t u; } c; c.f = f;
    uint32_t u = c.u;
    uint32_t r = (u + 0x7FFFu + ((u >> 16) & 1u)) >> 16;  // RNE
    return (unsigned short)r;
}

// ---- fused GEMM: C[m][n] = sum_k leaky(x)[m][k]*Wt[n][k] (+bias for n<512) ----
__global__ __launch_bounds__(256) void gemm_pq(const float* __restrict__ x,
                                               const float* __restrict__ W,
                                               const float* __restrict__ bias,
                                               float* __restrict__ C) {
    __shared__ unsigned short As[TM * ASTR];   // 33792 B
    __shared__ unsigned short Bs[TN * ASTR];   // 33792 B  (67.6 KB -> 2 blocks/CU)
    const int bm = blockIdx.x;            // 0..23
    const int bn = blockIdx.y;            // 0..15
    const int tid = threadIdx.x;
    const int lane = tid & 63;
    const int w  = tid >> 6;
    const int wr = w >> 1, wc = w & 1;    // wave -> 32x32 quadrant
    const int l15 = lane & 15, l4 = lane >> 4;

    const float* xbase = x + (size_t)(bm * TM) * K_DIM;
    const float* wbase = (bn < 8) ? (W + (size_t)(bn * TN) * N_DIM)
                                  : (W + (size_t)(bn * TN - C_DIM) * N_DIM + C_DIM);

    f32x4 acc[2][2] = {};

    for (int ph = 0; ph < 2; ++ph) {
        __syncthreads();
        // stage A: 64 rows x 64 f32x4 chunks = 4096 chunks
#pragma unroll 4
        for (int r = 0; r < 16; ++r) {
            int q = tid + 256 * r;
            int row = q >> 6, kc4 = (q & 63) << 2;
            f32x4 v = *(const f32x4*)(xbase + (size_t)row * K_DIM + ph * KPH + kc4);
            short4v s;
#pragma unroll
            for (int e = 0; e < 4; ++e) {
                float f = v[e];
                f = f > 0.f ? f : 0.1f * f;
                s[e] = (short)f32_to_bf16(f);
            }
            *(short4v*)(&As[row * ASTR + kc4]) = s;
        }
        // stage B: 64 rows x 64 chunks = 4096 chunks
#pragma unroll 4
        for (int r = 0; r < 16; ++r) {
            int q = tid + 256 * r;
            int row = q >> 6, kc4 = (q & 63) << 2;
            f32x4 v = *(const f32x4*)(wbase + (size_t)row * N_DIM + ph * KPH + kc4);
            short4v s;
#pragma unroll
            for (int e = 0; e < 4; ++e) s[e] = (short)f32_to_bf16(v[e]);
            *(short4v*)(&Bs[row * ASTR + kc4]) = s;
        }
        __syncthreads();
#pragma unroll
        for (int kt = 0; kt < 8; ++kt) {
            short8 a[2], b[2];
#pragma unroll
            for (int m = 0; m < 2; ++m)
                a[m] = *(const short8*)(&As[(wr * 32 + m * 16 + l15) * ASTR + kt * 32 + l4 * 8]);
#pragma unroll
            for (int n = 0; n < 2; ++n)
                b[n] = *(const short8*)(&Bs[(wc * 32 + n * 16 + l15) * ASTR + kt * 32 + l4 * 8]);
#pragma unroll
            for (int m = 0; m < 2; ++m)
#pragma unroll
                for (int n = 0; n < 2; ++n)
                    acc[m][n] = __builtin_amdgcn_mfma_f32_16x16x32_bf16(a[m], b[n], acc[m][n], 0, 0, 0);
        }
    }

#pragma unroll
    for (int m = 0; m < 2; ++m) {
#pragma unroll
        for (int n = 0; n < 2; ++n) {
            int col = bn * TN + wc * 32 + n * 16 + l15;
            float bv = (bn < 8) ? bias[col] : 0.f;
#pragma unroll
            for (int e = 0; e < 4; ++e) {
                int row = bm * TM + wr * 32 + m * 16 + l4 * 4 + e;
                C[(size_t)row * N_DIM + col] = acc[m][n][e] + bv;
            }
        }
    }
}

// ---- combine: R4-best byte-for-byte (nt, q[12] hoisted, 6144 blocks) ----
__global__ __launch_bounds__(256) void combine_k(const f32x4* __restrict__ PQ4,
                                                 f32x4* __restrict__ out4) {
    const int jh   = blockIdx.x & 7;              // j-octant
    const int rest = blockIdx.x >> 3;             // 0..767
    const int g    = rest * 256 + threadIdx.x;    // 0..196607
    const uint32_t c4 = (uint32_t)g & 127u;
    const uint32_t rg = (uint32_t)g >> 7;         // i*16+b, 0..1535
    const uint32_t b  = rg & 15u;
    const uint32_t i  = rg >> 4;

    const f32x4 p = PQ4[(size_t)rg * 256u + c4];          // P[i*16+b][c4]
    const int j0 = jh * 12;
    const f32x4* qb = PQ4 + ((size_t)(j0 * 16u + b)) * 256u + 128u + c4;

    f32x4 q[12];
#pragma unroll
    for (int j = 0; j < 12; ++j) q[j] = qb[(size_t)j * 4096u];   // +16 rows per j

    f32x4* ob = out4 + ((size_t)(i * 96u + (uint32_t)j0) * 16u + b) * 128u + c4;
#pragma unroll
    for (int j = 0; j < 12; ++j)
        __builtin_nontemporal_store(p + q[j], ob + (size_t)j * 2048u);  // +32KB per j
}

extern "C" void kernel_launch(void* const* d_in, const int* in_sizes, int n_in,
                              void* d_out, int out_size, void* d_ws, size_t ws_size,
                              hipStream_t stream) {
    const float* x    = (const float*)d_in[0];
    const float* W    = (const float*)d_in[1];
    const float* bias = (const float*)d_in[2];
    float* out = (float*)d_out;

    float* PQ = (float*)d_ws;                      // 1536 x 1024 f32 = 6,291,456 B

    dim3 g(M_DIM / TM, N_DIM / TN);                // 24 x 16 = 384 blocks
    gemm_pq<<<g, 256, 0, stream>>>(x, W, bias, PQ);
    combine_k<<<6144, 256, 0, stream>>>((const f32x4*)PQ, (f32x4*)out);
}